// Round 1
// baseline (11030.388 us; speedup 1.0000x reference)
//
#include <hip/hip_runtime.h>

#define Bn 64
#define Cn 128
#define Hn 36
#define Wn 100
#define KSn 9

#define B_STRIDE (Cn * Hn * Wn)  // 460800
#define C_STRIDE (Hn * Wn)       // 3600

// prepped weight layout: [coq(4)][ci(128)][coset(8)][j(4)*9+k] -> 36 dwords per entry
#define PW_SIZE (Cn * Cn * KSn)  // 147456 floats per direction

// ---------------- copy x -> buf ----------------
__global__ void __launch_bounds__(256) k_copy(const float4* __restrict__ s,
                                              float4* __restrict__ d, int n4) {
  int i = blockIdx.x * 256 + threadIdx.x;
  if (i < n4) d[i] = s[i];
}

// ---------------- weight prep: [co][ci][k] -> [coq][ci][coset][j*9+k] ----
__global__ void __launch_bounds__(256) k_prep3(const float* __restrict__ w,
                                               float* __restrict__ o) {
  int i = blockIdx.x * 256 + threadIdx.x;
  if (i >= PW_SIZE) return;
  int k = i % 9;
  int j = (i / 9) & 3;
  int coset = (i / 36) & 7;
  int ci = (i / 288) & 127;
  int coq = i / 36864;
  o[i] = w[((coq * 32 + coset * 4 + j) * Cn + ci) * KSn + k];
}

// ---------------- H-direction step ----------------
// grid (Bn, 4), block 256. Block = 32 co x 100 w, all 128 ci.
// Thread: coset = t&7 (4 co), wgrp = t>>3 (4 w). Weights staged in LDS chunks
// of 8 ci with register prefetch; read as uniform conflict-free b128.
__global__ void __launch_bounds__(256) k_hstep3(float* __restrict__ buf,
                                                const float* __restrict__ wp,
                                                int hp, int hc) {
  __shared__ float prev[Cn][Wn + 8];  // 55296 B
  __shared__ float wch[8][8][36];     // 9216 B : [ci8][coset][j*9+k]
  const int b = blockIdx.x, coq = blockIdx.y, t = threadIdx.x;
  const int coset = t & 7;
  const int wgrp = t >> 3;  // 0..31 (25 produce valid output)
  const int w0r = wgrp * 4;
  const int w0 = (w0r > 96) ? 96 : w0r;  // clamp so p-reads stay in [0,108)

  // stage prev row (padded +-4 with zeros)
  const float* rb = buf + ((size_t)b * Cn * Hn + hp) * Wn;
  for (int g = t; g < Cn * 25; g += 256) {
    int ci = g / 25, wq = g % 25;
    *(float4*)&prev[ci][4 + wq * 4] = *(const float4*)(rb + (size_t)ci * C_STRIDE + wq * 4);
  }
  for (int g = t; g < Cn * 8; g += 256) {
    int ci = g >> 3, s = g & 7;
    prev[ci][(s < 4) ? s : (Wn + s)] = 0.f;
  }

  const float* wsrc = wp + (size_t)coq * (Cn * 288);
  float4 wstage[3];
  {
    const float4* s4 = (const float4*)wsrc;
#pragma unroll
    for (int r = 0; r < 3; ++r) {
      int g = t + 256 * r;
      if (g < 576) wstage[r] = s4[g];
    }
  }

  float acc[4][4] = {};
  float4* d4 = (float4*)&wch[0][0][0];
  for (int c = 0; c < 16; ++c) {
    __syncthreads();  // prior chunk fully consumed (also covers prev staging at c=0)
#pragma unroll
    for (int r = 0; r < 3; ++r) {
      int g = t + 256 * r;
      if (g < 576) d4[g] = wstage[r];
    }
    __syncthreads();
    if (c < 15) {  // prefetch next chunk into regs; latency hides under FMAs
      const float4* s4 = (const float4*)(wsrc + (c + 1) * 2304);
#pragma unroll
      for (int r = 0; r < 3; ++r) {
        int g = t + 256 * r;
        if (g < 576) wstage[r] = s4[g];
      }
    }
#pragma unroll 2
    for (int c8 = 0; c8 < 8; ++c8) {
      const int ci = c * 8 + c8;
      float p[12];  // 16B-aligned -> 3x ds_read_b128, banks 4g..4g+3 (conflict-free)
#pragma unroll
      for (int q = 0; q < 12; ++q) p[q] = prev[ci][w0 + q];
      const float* wr = &wch[c8][coset][0];  // 144B stride -> 9x b128, conflict-free
      float wreg[36];
#pragma unroll
      for (int r = 0; r < 36; ++r) wreg[r] = wr[r];
#pragma unroll
      for (int j = 0; j < 4; ++j)
#pragma unroll
        for (int k = 0; k < KSn; ++k) {
          const float wv = wreg[j * 9 + k];
#pragma unroll
          for (int i = 0; i < 4; ++i) acc[j][i] = fmaf(p[i + k], wv, acc[j][i]);
        }
    }
  }

  if (w0r <= 96) {  // wgrps 25..31 are clamped duplicates: masked off
    float* ob = buf + ((size_t)(b * Cn + coq * 32 + coset * 4) * Hn + hc) * Wn + w0;
#pragma unroll
    for (int j = 0; j < 4; ++j) {
      float4* op = (float4*)(ob + (size_t)j * C_STRIDE);
      float4 o = *op;
      o.x += fmaxf(acc[j][0], 0.f);
      o.y += fmaxf(acc[j][1], 0.f);
      o.z += fmaxf(acc[j][2], 0.f);
      o.w += fmaxf(acc[j][3], 0.f);
      *op = o;
    }
  }
}

// ---------------- W-direction step (transposed layout [b][c][w][h]) ----
// grid (Bn, 4), block 256. Block = 32 co x 36 h; 4 waves split ci (32 each),
// LDS reduction at the end. Thread: coset = l&7 (4 co), hgrp = l>>3 (5 h).
__global__ void __launch_bounds__(256) k_wstep3(float* __restrict__ tb,
                                                const float* __restrict__ wp,
                                                int wpos, int wc) {
  __shared__ float prev[Cn][Hn + 8];   // 22528 B
  __shared__ float wch[4][8][8][36];   // 36864 B : [wv][ci8][coset][36]; reused for reduce
  const int b = blockIdx.x, coq = blockIdx.y, t = threadIdx.x;
  const int wv = t >> 6, l = t & 63;
  const int coset = l & 7, hgrp = l >> 3;
  const int h0r = hgrp * 5;
  const int h0 = (h0r > 31) ? 31 : h0r;  // clamp so p-reads stay in [0,44)

  const float* cb = tb + ((size_t)b * Cn * Wn + wpos) * Hn;
  for (int g = t; g < Cn * 9; g += 256) {
    int ci = g / 9, hq = g % 9;
    *(float4*)&prev[ci][4 + hq * 4] = *(const float4*)(cb + (size_t)ci * C_STRIDE + hq * 4);
  }
  for (int g = t; g < Cn * 8; g += 256) {
    int ci = g >> 3, s = g & 7;
    prev[ci][(s < 4) ? s : (Hn + s)] = 0.f;
  }

  const float* wsrc = wp + (size_t)coq * (Cn * 288);
  float4 wstage[9];  // 2304 float4 per chunk-set / 256 threads = 9 exact
#pragma unroll
  for (int r = 0; r < 9; ++r) {
    int g = t + 256 * r;
    int gw = g / 576, rem = g % 576;
    wstage[r] = *((const float4*)wsrc + (size_t)(gw * 32) * 72 + rem);
  }

  float acc[4][5] = {};
  float4* d4 = (float4*)&wch[0][0][0][0];
  for (int c = 0; c < 4; ++c) {
    __syncthreads();
#pragma unroll
    for (int r = 0; r < 9; ++r) d4[t + 256 * r] = wstage[r];
    __syncthreads();
    if (c < 3) {
#pragma unroll
      for (int r = 0; r < 9; ++r) {
        int g = t + 256 * r;
        int gw = g / 576, rem = g % 576;
        wstage[r] = *((const float4*)wsrc + (size_t)(gw * 32 + (c + 1) * 8) * 72 + rem);
      }
    }
#pragma unroll 2
    for (int c8 = 0; c8 < 8; ++c8) {
      const int ci = wv * 32 + c * 8 + c8;
      float p[13];  // stride-5 addresses across hgrps -> conflict-free
#pragma unroll
      for (int q = 0; q < 13; ++q) p[q] = prev[ci][h0 + q];
      const float* wr = &wch[wv][c8][coset][0];
      float wreg[36];
#pragma unroll
      for (int r = 0; r < 36; ++r) wreg[r] = wr[r];
#pragma unroll
      for (int j = 0; j < 4; ++j)
#pragma unroll
        for (int k = 0; k < KSn; ++k) {
          const float wvv = wreg[j * 9 + k];
#pragma unroll
          for (int i = 0; i < 5; ++i) acc[j][i] = fmaf(p[i + k], wvv, acc[j][i]);
        }
    }
  }

  // cross-wave ci reduction via LDS (reuse wch region)
  __syncthreads();
  float* red = &wch[0][0][0][0];  // [wv][l][j*5+i], 20 dwords per (wv,l)
#pragma unroll
  for (int j = 0; j < 4; ++j)
#pragma unroll
    for (int i = 0; i < 5; ++i) red[(wv * 64 + l) * 20 + j * 5 + i] = acc[j][i];
  __syncthreads();
  {
    const int oh = t & 7, oc = t >> 3;
    const int rj = oc & 3, rcs = oc >> 2;
    const int rl = oh * 8 + rcs;
    const int oh0r = oh * 5;
    const int oh0 = (oh0r > 31) ? 31 : oh0r;
    float v[5];
#pragma unroll
    for (int i = 0; i < 5; ++i) v[i] = red[rl * 20 + rj * 5 + i];
#pragma unroll
    for (int w2 = 1; w2 < 4; ++w2)
#pragma unroll
      for (int i = 0; i < 5; ++i) v[i] += red[(w2 * 64 + rl) * 20 + rj * 5 + i];
    const int co = coq * 32 + rcs * 4 + rj;
    float* ob = tb + ((size_t)(b * Cn + co) * Wn + wc) * Hn;
#pragma unroll
    for (int i = 0; i < 5; ++i) {
      const int h = oh0 + i;
      if (h >= oh0r && h < Hn) ob[h] += fmaxf(v[i], 0.f);  // mask kills clamped dups
    }
  }
}

// ---------------- transposes ----------------
__global__ void __launch_bounds__(256) k_t_hw2wh(const float* __restrict__ in,
                                                 float* __restrict__ out) {
  __shared__ float tile[Hn][Wn + 1];
  const int bc = blockIdx.x;
  const float* ib = in + (size_t)bc * C_STRIDE;
  float* ob = out + (size_t)bc * C_STRIDE;
  for (int f = threadIdx.x; f < Hn * Wn; f += 256) tile[f / Wn][f % Wn] = ib[f];
  __syncthreads();
  for (int f = threadIdx.x; f < Hn * Wn; f += 256) {
    int w = f / Hn, h = f % Hn;
    ob[f] = tile[h][w];
  }
}
__global__ void __launch_bounds__(256) k_t_wh2hw(const float* __restrict__ in,
                                                 float* __restrict__ out) {
  __shared__ float tile[Hn][Wn + 1];
  const int bc = blockIdx.x;
  const float* ib = in + (size_t)bc * C_STRIDE;
  float* ob = out + (size_t)bc * C_STRIDE;
  for (int f = threadIdx.x; f < Hn * Wn; f += 256) {
    int w = f / Hn, h = f % Hn;
    tile[h][w] = ib[f];
  }
  __syncthreads();
  for (int f = threadIdx.x; f < Hn * Wn; f += 256) ob[f] = tile[f / Wn][f % Wn];
}

// ---------------- fallback kernels (round-1, proven) ----------------
__global__ void __launch_bounds__(128) k_hstep(float* __restrict__ buf,
                                               const float* __restrict__ wt,
                                               int hp, int hc) {
  __shared__ float prev[Cn][Wn + 8];
  const int b = blockIdx.x;
  const int cog = blockIdx.y;
  const int t = threadIdx.x;
  const float* rb = buf + ((size_t)b * Cn * Hn + hp) * Wn;
  for (int g = t; g < Cn * (Wn / 4); g += 128) {
    int ci = g / 25, wq = g % 25;
    float4 v = *(const float4*)(rb + (size_t)ci * C_STRIDE + wq * 4);
    *(float4*)&prev[ci][4 + wq * 4] = v;
  }
  for (int g = t; g < Cn * 8; g += 128) {
    int ci = g >> 3, s = g & 7;
    prev[ci][(s < 4) ? s : (Wn + s)] = 0.f;
  }
  __syncthreads();
  if (t >= Wn) return;
  float acc[8] = {0.f, 0.f, 0.f, 0.f, 0.f, 0.f, 0.f, 0.f};
  const float* wb = wt + (size_t)cog * 8 * Cn * KSn;
  for (int ci = 0; ci < Cn; ++ci) {
    float p[KSn];
#pragma unroll
    for (int k = 0; k < KSn; ++k) p[k] = prev[ci][t + k];
#pragma unroll
    for (int j = 0; j < 8; ++j) {
      const float* w9 = wb + ((size_t)j * Cn + ci) * KSn;
#pragma unroll
      for (int k = 0; k < KSn; ++k) acc[j] = fmaf(p[k], w9[k], acc[j]);
    }
  }
  float* ob = buf + ((size_t)(b * Cn + cog * 8) * Hn + hc) * Wn + t;
#pragma unroll
  for (int j = 0; j < 8; ++j) ob[(size_t)j * C_STRIDE] += fmaxf(acc[j], 0.f);
}
__global__ void __launch_bounds__(128) k_wstep_d(float* __restrict__ buf,
                                                 const float* __restrict__ wt,
                                                 int wpos, int wc) {
  __shared__ float prev[Cn][Hn + 8];
  const int b = blockIdx.x;
  const int cog = blockIdx.y;
  const int t = threadIdx.x;
  const int h = t & 63;
  const int jb = __builtin_amdgcn_readfirstlane((t >> 6) * 4);
  for (int g = t; g < Cn * Hn; g += 128) {
    int ci = g / Hn, hh = g % Hn;
    prev[ci][4 + hh] = buf[((size_t)(b * Cn + ci) * Hn + hh) * Wn + wpos];
  }
  for (int g = t; g < Cn * 8; g += 128) {
    int ci = g >> 3, s = g & 7;
    prev[ci][(s < 4) ? s : (Hn + s)] = 0.f;
  }
  __syncthreads();
  if (h >= Hn) return;
  float acc[4] = {0.f, 0.f, 0.f, 0.f};
  const float* wb = wt + (size_t)(cog * 8 + jb) * Cn * KSn;
  for (int ci = 0; ci < Cn; ++ci) {
    float p[KSn];
#pragma unroll
    for (int k = 0; k < KSn; ++k) p[k] = prev[ci][h + k];
#pragma unroll
    for (int j = 0; j < 4; ++j) {
      const float* w9 = wb + ((size_t)j * Cn + ci) * KSn;
#pragma unroll
      for (int k = 0; k < KSn; ++k) acc[j] = fmaf(p[k], w9[k], acc[j]);
    }
  }
  float* ob = buf + ((size_t)(b * Cn + cog * 8 + jb) * Hn + h) * Wn + wc;
#pragma unroll
  for (int j = 0; j < 4; ++j) ob[(size_t)j * C_STRIDE] += fmaxf(acc[j], 0.f);
}

extern "C" void kernel_launch(void* const* d_in, const int* in_sizes, int n_in,
                              void* d_out, int out_size, void* d_ws, size_t ws_size,
                              hipStream_t stream) {
  (void)in_sizes; (void)n_in; (void)out_size;
  const float* x  = (const float*)d_in[0];
  const float* wd = (const float*)d_in[1];
  const float* wu = (const float*)d_in[2];
  const float* wr = (const float*)d_in[3];
  const float* wl = (const float*)d_in[4];
  float* buf = (float*)d_out;
  const size_t nelem = (size_t)Bn * B_STRIDE;  // 29,491,200 floats
  const size_t need = (nelem + 4 * (size_t)PW_SIZE) * 4;

  k_copy<<<(int)(nelem / 4 + 255) / 256, 256, 0, stream>>>(
      (const float4*)x, (float4*)buf, (int)(nelem / 4));

  if (ws_size >= need) {
    float* tb  = (float*)d_ws;  // transposed buffer
    float* pwd = tb + nelem;    // prepped weights
    float* pwu = pwd + PW_SIZE;
    float* pwr = pwu + PW_SIZE;
    float* pwl = pwr + PW_SIZE;

    const int pg = (PW_SIZE + 255) / 256;
    k_prep3<<<pg, 256, 0, stream>>>(wd, pwd);
    k_prep3<<<pg, 256, 0, stream>>>(wu, pwu);
    k_prep3<<<pg, 256, 0, stream>>>(wr, pwr);
    k_prep3<<<pg, 256, 0, stream>>>(wl, pwl);

    dim3 g4(Bn, 4);  // 256 blocks of 256
    for (int hh = 1; hh < Hn; ++hh)
      k_hstep3<<<g4, 256, 0, stream>>>(buf, pwd, hh - 1, hh);
    for (int hh = Hn - 2; hh >= 0; --hh)
      k_hstep3<<<g4, 256, 0, stream>>>(buf, pwu, hh + 1, hh);

    k_t_hw2wh<<<Bn * Cn, 256, 0, stream>>>(buf, tb);
    for (int ww = 1; ww < Wn; ++ww)
      k_wstep3<<<g4, 256, 0, stream>>>(tb, pwr, ww - 1, ww);
    for (int ww = Wn - 2; ww >= 0; --ww)
      k_wstep3<<<g4, 256, 0, stream>>>(tb, pwl, ww + 1, ww);
    k_t_wh2hw<<<Bn * Cn, 256, 0, stream>>>(tb, buf);
  } else {
    // proven round-1 fallback (raw weights, direct W)
    dim3 g8(Bn, Cn / 8);
    for (int hh = 1; hh < Hn; ++hh)
      k_hstep<<<g8, 128, 0, stream>>>(buf, wd, hh - 1, hh);
    for (int hh = Hn - 2; hh >= 0; --hh)
      k_hstep<<<g8, 128, 0, stream>>>(buf, wu, hh + 1, hh);
    for (int ww = 1; ww < Wn; ++ww)
      k_wstep_d<<<g8, 128, 0, stream>>>(buf, wr, ww - 1, ww);
    for (int ww = Wn - 2; ww >= 0; --ww)
      k_wstep_d<<<g8, 128, 0, stream>>>(buf, wl, ww + 1, ww);
  }
}